// Round 18
// baseline (106.304 us; speedup 1.0000x reference)
//
#include <hip/hip_runtime.h>
#include <hip/hip_bf16.h>

// ---------- problem constants ----------
constexpr int Bb   = 2;
constexpr int Ss   = 2048;
constexpr int Dm   = 1024;
constexpr int Hh   = 16;
constexpr int Hd   = 64;
constexpr int Mtot = Bb * Ss;      // 4096
constexpr int NCH  = Ss / 64;      // 32 chunks of 64

typedef __bf16 bf16x8 __attribute__((ext_vector_type(8)));
typedef float  f32x4  __attribute__((ext_vector_type(4)));
typedef float  f32x16 __attribute__((ext_vector_type(16)));
typedef __attribute__((address_space(1))) unsigned int u32_as1;
typedef __attribute__((address_space(3))) unsigned int u32_as3;

__device__ __forceinline__ void gload_lds16(const void* g, void* l) {
  __builtin_amdgcn_global_load_lds((const u32_as1*)g, (u32_as3*)l, 16, 0, 0);
}

__device__ __forceinline__ unsigned short f2bf(float f) {
  union { float f; unsigned u; } x; x.f = f;
  unsigned r = x.u + 0x7fffu + ((x.u >> 16) & 1u);   // RNE
  return (unsigned short)(r >> 16);
}

__device__ __forceinline__ float bf2f(unsigned short s) {
  union { unsigned u; float f; } x; x.u = ((unsigned)s) << 16;
  return x.f;
}

// ---------- fused prep: n-projection + x->bf16 + all three weight transposes ----------
__global__ __launch_bounds__(256) void k_prep(
    const float* __restrict__ x, const float* __restrict__ Wn, const float* __restrict__ bn,
    float* __restrict__ invn, unsigned short* __restrict__ xb,
    const float* __restrict__ Wqk, const float* __restrict__ Wv, const float* __restrict__ Wo,
    unsigned short* __restrict__ wprojT, unsigned short* __restrict__ woT) {
  __shared__ __align__(16) char smem[16384];
  int bi = blockIdx.x;
  int tid = threadIdx.x;
  if (bi < 1024) {
    float (*xl)[1024] = (float(*)[1024])smem;
    int w = tid >> 6, lane = tid & 63;
    int row = bi * 4 + w;                       // [0, 4096)
    const float4* x4 = (const float4*)(x + (size_t)row * Dm);
    ushort4* xb4 = (ushort4*)(xb + (size_t)row * Dm);
#pragma unroll
    for (int j = 0; j < 4; ++j) {
      float4 v = x4[j * 64 + lane];
      *(float4*)&xl[w][(j * 64 + lane) * 4] = v;
      ushort4 o;
      o.x = f2bf(v.x); o.y = f2bf(v.y); o.z = f2bf(v.z); o.w = f2bf(v.w);
      xb4[j * 64 + lane] = o;
    }
    __syncthreads();
    const float4* Wn4 = (const float4*)Wn;
    f32x4 sum = {0.f, 0.f, 0.f, 0.f};
#pragma unroll 4
    for (int j = 0; j < 64; ++j) {
      float xv = xl[w][j * 16 + (lane >> 2)];
      float4 wv = Wn4[j * 64 + lane];
      sum[0] += xv * wv.x; sum[1] += xv * wv.y; sum[2] += xv * wv.z; sum[3] += xv * wv.w;
    }
#pragma unroll
    for (int m = 4; m < 64; m <<= 1) {
      sum[0] += __shfl_xor(sum[0], m);
      sum[1] += __shfl_xor(sum[1], m);
      sum[2] += __shfl_xor(sum[2], m);
      sum[3] += __shfl_xor(sum[3], m);
    }
    if (lane < 4) {
      int b = row >> 11, s = row & 2047;
#pragma unroll
      for (int e = 0; e < 4; ++e) {
        int h = lane * 4 + e;
        float nv = sum[e] + bn[h];
        invn[((size_t)(b * Hh + h)) * Ss + s] = expf(-nv);
      }
    }
  } else {
    float (*t)[33] = (float(*)[33])smem;
    int ti = bi - 1024;
    const float* W; unsigned short* Wt; int N, n0, k0;
    if (ti < 2048) {
      W = Wqk; Wt = wprojT; N = 2048;
      n0 = (ti & 63) * 32; k0 = (ti >> 6) * 32;
    } else if (ti < 3072) {
      int l = ti - 2048; W = Wv; Wt = wprojT + (size_t)2048 * 1024; N = 1024;
      n0 = (l & 31) * 32; k0 = (l >> 5) * 32;
    } else {
      int l = ti - 3072; W = Wo; Wt = woT; N = 1024;
      n0 = (l & 31) * 32; k0 = (l >> 5) * 32;
    }
    int tx = tid & 31, ty = tid >> 5;
#pragma unroll
    for (int j = 0; j < 32; j += 8)
      t[ty + j][tx] = W[(size_t)(k0 + ty + j) * N + n0 + tx];
    __syncthreads();
#pragma unroll
    for (int j = 0; j < 32; j += 8)
      Wt[(size_t)(n0 + ty + j) * 1024 + k0 + tx] = f2bf(t[tx][ty + j]);
  }
}

// ---------- fused projection GEMM: 128x128, 32x32x16 MFMA (R17 proven) ----------
__global__ __launch_bounds__(256, 4) void k_gemm_proj(
    const unsigned short* __restrict__ A, const unsigned short* __restrict__ BT,
    const float* __restrict__ bias0, const float* __restrict__ bias1,
    void* __restrict__ out0, void* __restrict__ out1, void* __restrict__ out2,
    void* __restrict__ out3, int M, int N, int K) {
  __shared__ __align__(16) unsigned short SMEM[2 * 128 * 64];   // 32 KB, reused by epilogue
  unsigned short* As = SMEM;
  unsigned short* Bs = SMEM + 128 * 64;
  int tid = threadIdx.x, w = tid >> 6, lane = tid & 63;
  int bid = blockIdx.y * gridDim.x + blockIdx.x;   // 0..767
  int xcd = bid & 7, idx = bid >> 3;               // idx 0..95
  int m0 = (xcd * 4 + (idx & 3)) * 128;
  int n0 = (idx >> 2) * 128;
  int wm = w >> 1, wn = w & 1;
  f32x16 acc[2][2] = {};

  int g = lane >> 5;                               // k-half within 16-k granule pair
  int l31 = lane & 31;

  int csrc = 8 * ((lane & 7) ^ (lane >> 3));       // pre-swizzled source column (elements)
  int rst  = w * 8 + (lane >> 3);                  // staging row base (+ i*32)

  for (int kt = 0; kt < (K >> 6); ++kt) {
#pragma unroll
    for (int i = 0; i < 4; ++i) {
      int r = i * 32 + rst;
      gload_lds16(A + (size_t)(m0 + r) * K + kt * 64 + csrc, As + i * 2048 + w * 512);
    }
#pragma unroll
    for (int i = 0; i < 4; ++i) {
      int r = i * 32 + rst;
      gload_lds16(BT + (size_t)(n0 + r) * K + kt * 64 + csrc, Bs + i * 2048 + w * 512);
    }
    __syncthreads();
#pragma unroll
    for (int s = 0; s < 4; ++s) {
      bf16x8 am[2], bn2[2];
#pragma unroll
      for (int mi = 0; mi < 2; ++mi) {
        int R = wm * 64 + mi * 32 + l31;
        am[mi] = *(const bf16x8*)((const char*)As + R * 128 + 16 * (((s * 2 + g) ^ (R & 7))));
      }
#pragma unroll
      for (int ni = 0; ni < 2; ++ni) {
        int R = wn * 64 + ni * 32 + l31;
        bn2[ni] = *(const bf16x8*)((const char*)Bs + R * 128 + 16 * (((s * 2 + g) ^ (R & 7))));
      }
#pragma unroll
      for (int mi = 0; mi < 2; ++mi)
#pragma unroll
        for (int ni = 0; ni < 2; ++ni)
          acc[mi][ni] = __builtin_amdgcn_mfma_f32_32x32x16_bf16(am[mi], bn2[ni], acc[mi][ni], 0, 0, 0);
    }
    __syncthreads();   // WAR seal; after last iter SMEM is dead -> epilogue may reuse
  }

  // ---- epilogue (32x32 C/D mapping, R16/R17-verified) ----
  int nfirst = n0 + wn * 64;                 // multiple of 64, wave-uniform
  int region = nfirst >> 10;
  int bI = m0 >> 11;                         // block-uniform batch
  int tb = (m0 & 2047) + wm * 64;            // wave's t-base within batch
  unsigned short* eplds = SMEM + w * 4096;   // per-wave 64x64 ushort slice (8 KB)

#pragma unroll
  for (int mi = 0; mi < 2; ++mi) {
#pragma unroll
    for (int ni = 0; ni < 2; ++ni) {
      int n = nfirst + ni * 32 + l31;
      float bb = (region < 2) ? bias0[n] : bias1[n - 2048];
      if (region <= 1) {
#pragma unroll
        for (int reg = 0; reg < 16; ++reg) {
          int tl = mi * 32 + (reg & 3) + 8 * (reg >> 2) + 4 * g;   // 0..63
          int col = ni * 32 + l31;                                 // 0..63 (= d)
          eplds[tl * 64 + (col ^ ((tl & 7) << 3))] = f2bf(acc[mi][ni][reg] + bb);
        }
        if (region == 1) {  // kT [bh][d][t] direct (t-contiguous reg-quads)
          int h = (n >> 6) & 15, d = n & 63;
#pragma unroll
          for (int q4 = 0; q4 < 4; ++q4) {
            int t = tb + mi * 32 + 8 * q4 + 4 * g;
            ushort4 o;
            o.x = f2bf(acc[mi][ni][4 * q4 + 0] + bb);
            o.y = f2bf(acc[mi][ni][4 * q4 + 1] + bb);
            o.z = f2bf(acc[mi][ni][4 * q4 + 2] + bb);
            o.w = f2bf(acc[mi][ni][4 * q4 + 3] + bb);
            *(ushort4*)((unsigned short*)out2 + ((size_t)(bI * Hh + h) * Hd + d) * Ss + t) = o;
          }
        }
      } else {            // vT [bh][d][t] direct
        int h = (n >> 6) & 15, d = n & 63;
#pragma unroll
        for (int q4 = 0; q4 < 4; ++q4) {
          int t = tb + mi * 32 + 8 * q4 + 4 * g;
          ushort4 o;
          o.x = f2bf(acc[mi][ni][4 * q4 + 0] + bb);
          o.y = f2bf(acc[mi][ni][4 * q4 + 1] + bb);
          o.z = f2bf(acc[mi][ni][4 * q4 + 2] + bb);
          o.w = f2bf(acc[mi][ni][4 * q4 + 3] + bb);
          *(ushort4*)((unsigned short*)out3 + ((size_t)(bI * Hh + h) * Hd + d) * Ss + t) = o;
        }
      }
    }
  }
  if (region <= 1) {
    asm volatile("" ::: "memory");           // order LDS reads after writes (wave-private slice)
    int tl = lane;                           // one 128B row per lane
    int t = tb + tl;
    int h = (nfirst >> 6) & 15;
    unsigned short* dst = ((region == 0) ? (unsigned short*)out0 : (unsigned short*)out1)
                        + (((size_t)(bI * Hh + h)) * Ss + t) * Hd;
#pragma unroll
    for (int c = 0; c < 8; ++c) {
      int col = (c * 8) ^ ((tl & 7) << 3);
      *(float4*)(dst + c * 8) = *(const float4*)(eplds + tl * 64 + col);
    }
  }
}

// ---------- output GEMM: 64x128 tile, 2-phase dbuf + XCD swizzle, 32x32x16 MFMA ----------
// Same fragment algebra as proj: elem(r,c) at byte r*128 + (2c ^ ((r&7)<<4));
// fragment byte = R*128 + 16*((s*2+g)^(R&7)); C/D row = (reg&3)+8*(reg>>2)+4*g.
__global__ __launch_bounds__(256, 3) void k_gemm_o(
    const unsigned short* __restrict__ A, const unsigned short* __restrict__ BT,
    const float* __restrict__ bias, float* __restrict__ out) {
  constexpr int K = 1024, N = 1024;
  __shared__ __align__(16) unsigned short As[2][64 * 64];
  __shared__ __align__(16) unsigned short Bs[2][128 * 64];
  int tid = threadIdx.x, w = tid >> 6, lane = tid & 63;
  int bid = blockIdx.y * gridDim.x + blockIdx.x;   // 0..511
  int xcd = bid & 7, idx = bid >> 3;               // 0..63
  int m0 = (xcd * 8 + (idx & 7)) * 64;
  int n0 = (idx >> 3) * 128;
  int wm = w >> 1, wn = w & 1;    // waves: 2 over M(32 each), 2 over N(64 each)
  f32x16 acc[2] = {};             // ni in {0,1}: wave tile 32M x 64N

  int g = lane >> 5;
  int l31 = lane & 31;
  int csrc = 8 * ((lane & 7) ^ (lane >> 3));
  int rst  = w * 8 + (lane >> 3);

  auto STAGE = [&](int kt, int cur) {
#pragma unroll
    for (int i = 0; i < 2; ++i) {
      int r = i * 32 + rst;
      gload_lds16(A + (size_t)(m0 + r) * K + kt * 64 + csrc, As[cur] + i * 2048 + w * 512);
    }
#pragma unroll
    for (int i = 0; i < 4; ++i) {
      int r = i * 32 + rst;
      gload_lds16(BT + (size_t)(n0 + r) * K + kt * 64 + csrc, Bs[cur] + i * 2048 + w * 512);
    }
  };

  constexpr int NT = K >> 6;
  STAGE(0, 0);
  __syncthreads();
  for (int kt = 0; kt < NT; ++kt) {
    int cur = kt & 1;
    if (kt + 1 < NT) STAGE(kt + 1, cur ^ 1);
#pragma unroll
    for (int s = 0; s < 4; ++s) {
      int Ra = wm * 32 + l31;
      bf16x8 am = *(const bf16x8*)((const char*)As[cur] + Ra * 128 + 16 * (((s * 2 + g) ^ (Ra & 7))));
      bf16x8 bn2[2];
#pragma unroll
      for (int ni = 0; ni < 2; ++ni) {
        int R = wn * 64 + ni * 32 + l31;
        bn2[ni] = *(const bf16x8*)((const char*)Bs[cur] + R * 128 + 16 * (((s * 2 + g) ^ (R & 7))));
      }
#pragma unroll
      for (int ni = 0; ni < 2; ++ni)
        acc[ni] = __builtin_amdgcn_mfma_f32_32x32x16_bf16(am, bn2[ni], acc[ni], 0, 0, 0);
    }
    __syncthreads();
  }

#pragma unroll
  for (int ni = 0; ni < 2; ++ni) {
    int n = n0 + wn * 64 + ni * 32 + l31;
    float bb = bias[n];
#pragma unroll
    for (int reg = 0; reg < 16; ++reg) {
      int m = m0 + wm * 32 + (reg & 3) + 8 * (reg >> 2) + 4 * g;
      out[(size_t)m * N + n] = acc[ni][reg] + bb;
    }
  }
}

// ---------- pass A1: per-chunk gram ----------
__global__ __launch_bounds__(64) void k_gram(
    const unsigned short* __restrict__ vT, const unsigned short* __restrict__ kT,
    unsigned short* __restrict__ G) {
  int lane = threadIdx.x;
  int j = blockIdx.x, bh = blockIdx.y;
  int t0 = j * 64;
  const unsigned short* vb = vT + (size_t)bh * Hd * Ss;
  const unsigned short* kb = kT + (size_t)bh * Hd * Ss;
  unsigned short* g = G + ((size_t)bh * NCH + j) * 4096;

  bf16x8 af[4][2], bfr[4][2];
#pragma unroll
  for (int mt = 0; mt < 4; ++mt)
#pragma unroll
    for (int ks = 0; ks < 2; ++ks) {
      af[mt][ks]  = *(const bf16x8*)(vb + (size_t)(mt * 16 + (lane & 15)) * Ss + t0 + ks * 32 + (lane >> 4) * 8);
      bfr[mt][ks] = *(const bf16x8*)(kb + (size_t)(mt * 16 + (lane & 15)) * Ss + t0 + ks * 32 + (lane >> 4) * 8);
    }
  f32x4 acc[4][4] = {};
#pragma unroll
  for (int mt = 0; mt < 4; ++mt)
#pragma unroll
    for (int nt = 0; nt < 4; ++nt)
#pragma unroll
      for (int ks = 0; ks < 2; ++ks)
        acc[mt][nt] = __builtin_amdgcn_mfma_f32_16x16x32_bf16(af[mt][ks], bfr[nt][ks], acc[mt][nt], 0, 0, 0);
#pragma unroll
  for (int mt = 0; mt < 4; ++mt)
#pragma unroll
    for (int nt = 0; nt < 4; ++nt)
#pragma unroll
      for (int r = 0; r < 4; ++r)
        g[(mt * 16 + (lane >> 4) * 4 + r) * 64 + nt * 16 + (lane & 15)] = f2bf(acc[mt][nt][r]);
}

// ---------- pass A2: exclusive prefix over chunks ----------
__global__ __launch_bounds__(256) void k_prefix(
    const unsigned short* __restrict__ G, unsigned short* __restrict__ Sp) {
  int gidx = blockIdx.x * 256 + threadIdx.x;   // 32 bh * 4096 elems
  int bh = gidx >> 12, e = gidx & 4095;
  const unsigned short* gp = G + (size_t)bh * NCH * 4096 + e;
  unsigned short* sp = Sp + (size_t)bh * NCH * 4096 + e;
  float acc = 0.f;
#pragma unroll
  for (int j = 0; j < NCH; ++j) {
    sp[(size_t)j * 4096] = f2bf(acc);
    acc += bf2f(gp[(size_t)j * 4096]);
  }
}

// ---------- pass B: per-chunk attention ----------
__global__ __launch_bounds__(256, 6) void k_chunk_attn(
    const unsigned short* __restrict__ q, const unsigned short* __restrict__ k,
    const unsigned short* __restrict__ vT, const unsigned short* __restrict__ Sp,
    const float* __restrict__ invn, unsigned short* __restrict__ ctx) {
  __shared__ __align__(16) unsigned short P[4 * 16 * 64];
  int tid = threadIdx.x, w = tid >> 6, lane = tid & 63;
  int j = blockIdx.x, bh = blockIdx.y;
  int t0 = j * 64;
  const unsigned short* qb = q + (size_t)bh * Ss * Hd;
  const unsigned short* kb = k + (size_t)bh * Ss * Hd;
  const unsigned short* vb = vT + (size_t)bh * Hd * Ss;
  const unsigned short* sp = Sp + ((size_t)bh * NCH + j) * 4096;

  bf16x8 qf[2];
#pragma unroll
  for (int ks = 0; ks < 2; ++ks)
    qf[ks] = *(const bf16x8*)(qb + (size_t)(t0 + w * 16 + (lane & 15)) * Hd + ks * 32 + (lane >> 4) * 8);

  f32x4 acc[4] = {};
#pragma unroll
  for (int nt = 0; nt < 4; ++nt)
#pragma unroll
    for (int ks = 0; ks < 2; ++ks) {
      bf16x8 sf = *(const bf16x8*)(sp + (nt * 16 + (lane & 15)) * 64 + ks * 32 + (lane >> 4) * 8);
      acc[nt] = __builtin_amdgcn_mfma_f32_16x16x32_bf16(qf[ks], sf, acc[nt], 0, 0, 0);
    }

  f32x4 sacc[4] = {};
#pragma unroll
  for (int nt = 0; nt < 4; ++nt)
#pragma unroll
    for (int ks = 0; ks < 2; ++ks) {
      bf16x8 kf = *(const bf16x8*)(kb + (size_t)(t0 + nt * 16 + (lane & 15)) * Hd + ks * 32 + (lane >> 4) * 8);
      sacc[nt] = __builtin_amdgcn_mfma_f32_16x16x32_bf16(qf[ks], kf, sacc[nt], 0, 0, 0);
    }

#pragma unroll
  for (int nt = 0; nt < 4; ++nt)
#pragma unroll
    for (int r = 0; r < 4; ++r) {
      int row = (lane >> 4) * 4 + r;
      int s_local = nt * 16 + (lane & 15);
      float vv = (s_local <= w * 16 + row) ? sacc[nt][r] : 0.f;
      int cb = s_local * 2;
      int byte = w * 2048 + row * 128 + (cb ^ ((row & 7) << 4));
      *(unsigned short*)((char*)P + byte) = f2bf(vv);
    }
  asm volatile("" ::: "memory");

  bf16x8 pf[2];
#pragma unroll
  for (int ks = 0; ks < 2; ++ks) {
    int prow = lane & 15;
    int pcb = (ks * 32 + (lane >> 4) * 8) * 2;
    pf[ks] = *(const bf16x8*)((char*)P + w * 2048 + prow * 128 + (pcb ^ ((prow & 7) << 4)));
  }
#pragma unroll
  for (int dt = 0; dt < 4; ++dt)
#pragma unroll
    for (int ks = 0; ks < 2; ++ks) {
      bf16x8 vf = *(const bf16x8*)(vb + (size_t)(dt * 16 + (lane & 15)) * Ss + t0 + ks * 32 + (lane >> 4) * 8);
      acc[dt] = __builtin_amdgcn_mfma_f32_16x16x32_bf16(pf[ks], vf, acc[dt], 0, 0, 0);
    }

  int b = bh >> 4, h = bh & 15;
  float sc[4];
#pragma unroll
  for (int r = 0; r < 4; ++r)
    sc[r] = invn[(size_t)bh * Ss + t0 + w * 16 + (lane >> 4) * 4 + r];
#pragma unroll
  for (int dt = 0; dt < 4; ++dt)
#pragma unroll
    for (int r = 0; r < 4; ++r) {
      int t = t0 + w * 16 + (lane >> 4) * 4 + r;
      size_t m = (size_t)b * Ss + t;
      ctx[m * Dm + h * Hd + dt * 16 + (lane & 15)] = f2bf(acc[dt][r] * sc[r]);
    }
}

// ---------- launch ----------
extern "C" void kernel_launch(void* const* d_in, const int* in_sizes, int n_in,
                              void* d_out, int out_size, void* d_ws, size_t ws_size,
                              hipStream_t stream) {
  const float* x   = (const float*)d_in[0];
  const float* Wqk = (const float*)d_in[1];
  const float* bqk = (const float*)d_in[2];
  const float* Wv  = (const float*)d_in[3];
  const float* bv  = (const float*)d_in[4];
  const float* Wn  = (const float*)d_in[5];
  const float* bn  = (const float*)d_in[6];
  const float* Wo  = (const float*)d_in[7];
  const float* bo  = (const float*)d_in[8];

  char* ws = (char*)d_ws;
  size_t off = 0;
  unsigned short* xb    = (unsigned short*)(ws + off); off += (size_t)Mtot * Dm * 2;          // 8 MB
  unsigned short* wprojT= (unsigned short*)(ws + off); off += (size_t)3072 * 1024 * 2;        // 6 MB
  unsigned short* woT   = (unsigned short*)(ws + off); off += (size_t)1024 * 1024 * 2;        // 2 MB
  unsigned short* qbuf  = (unsigned short*)(ws + off); off += (size_t)Bb * Hh * Ss * Hd * 2;  // 8 MB
  unsigned short* kbuf  = (unsigned short*)(ws + off); off += (size_t)Bb * Hh * Ss * Hd * 2;  // 8 MB
  unsigned short* ktbuf = (unsigned short*)(ws + off); off += (size_t)Bb * Hh * Ss * Hd * 2;  // 8 MB
  unsigned short* vbuf  = (unsigned short*)(ws + off); off += (size_t)Bb * Hh * Ss * Hd * 2;  // 8 MB
  float* invn           = (float*)(ws + off);          off += (size_t)Bb * Hh * Ss * 4;       // 256 KB
  unsigned short* G     = (unsigned short*)(ws + off); off += (size_t)Bb * Hh * NCH * 4096 * 2; // 8 MB
  unsigned short* Sp    = (unsigned short*)(ws + off); off += (size_t)Bb * Hh * NCH * 4096 * 2; // 8 MB
  unsigned short* ctx   = xb;  // alias: xb dead after fused projection GEMM

  // 1) fused prep (one launch)
  k_prep<<<5120, 256, 0, stream>>>(x, Wn, bn, invn, xb, Wqk, Wv, Wo, wprojT, woT);

  // 2) fused q/k/v projections (N = 3072), 32x32x16 MFMA + R14 staging (768 blocks)
  k_gemm_proj<<<dim3(3072 / 128, Mtot / 128), 256, 0, stream>>>(
      xb, wprojT, bqk, bv, qbuf, kbuf, ktbuf, vbuf, Mtot, 3072, 1024);

  // 3) attention = parallel gram + parallel prefix + per-chunk
  k_gram<<<dim3(NCH, Bb * Hh), 64, 0, stream>>>(vbuf, ktbuf, G);
  k_prefix<<<(Bb * Hh * 4096) / 256, 256, 0, stream>>>(G, Sp);
  k_chunk_attn<<<dim3(NCH, Bb * Hh), 256, 0, stream>>>(qbuf, kbuf, vbuf, Sp, invn, ctx);

  // 4) output projection -> f32 d_out, 64x128 2-phase dbuf + XCD, 32x32x16 (512 blocks)
  k_gemm_o<<<dim3(1024 / 128, Mtot / 64), 256, 0, stream>>>(ctx, woT, bo, (float*)d_out);
}

// Round 19
// 102.052 us; speedup vs baseline: 1.0417x; 1.0417x over previous
//
#include <hip/hip_runtime.h>
#include <hip/hip_bf16.h>

// ---------- problem constants ----------
constexpr int Bb   = 2;
constexpr int Ss   = 2048;
constexpr int Dm   = 1024;
constexpr int Hh   = 16;
constexpr int Hd   = 64;
constexpr int Mtot = Bb * Ss;      // 4096
constexpr int NCH  = Ss / 64;      // 32 chunks of 64

typedef __bf16 bf16x8 __attribute__((ext_vector_type(8)));
typedef float  f32x4  __attribute__((ext_vector_type(4)));
typedef float  f32x16 __attribute__((ext_vector_type(16)));
typedef __attribute__((address_space(1))) unsigned int u32_as1;
typedef __attribute__((address_space(3))) unsigned int u32_as3;

__device__ __forceinline__ void gload_lds16(const void* g, void* l) {
  __builtin_amdgcn_global_load_lds((const u32_as1*)g, (u32_as3*)l, 16, 0, 0);
}

__device__ __forceinline__ unsigned short f2bf(float f) {
  union { float f; unsigned u; } x; x.f = f;
  unsigned r = x.u + 0x7fffu + ((x.u >> 16) & 1u);   // RNE
  return (unsigned short)(r >> 16);
}

__device__ __forceinline__ float bf2f(unsigned short s) {
  union { unsigned u; float f; } x; x.u = ((unsigned)s) << 16;
  return x.f;
}

// ---------- fused prep: n-projection + x->bf16 + all three weight transposes ----------
__global__ __launch_bounds__(256) void k_prep(
    const float* __restrict__ x, const float* __restrict__ Wn, const float* __restrict__ bn,
    float* __restrict__ invn, unsigned short* __restrict__ xb,
    const float* __restrict__ Wqk, const float* __restrict__ Wv, const float* __restrict__ Wo,
    unsigned short* __restrict__ wprojT, unsigned short* __restrict__ woT) {
  __shared__ __align__(16) char smem[16384];
  int bi = blockIdx.x;
  int tid = threadIdx.x;
  if (bi < 1024) {
    float (*xl)[1024] = (float(*)[1024])smem;
    int w = tid >> 6, lane = tid & 63;
    int row = bi * 4 + w;                       // [0, 4096)
    const float4* x4 = (const float4*)(x + (size_t)row * Dm);
    ushort4* xb4 = (ushort4*)(xb + (size_t)row * Dm);
#pragma unroll
    for (int j = 0; j < 4; ++j) {
      float4 v = x4[j * 64 + lane];
      *(float4*)&xl[w][(j * 64 + lane) * 4] = v;
      ushort4 o;
      o.x = f2bf(v.x); o.y = f2bf(v.y); o.z = f2bf(v.z); o.w = f2bf(v.w);
      xb4[j * 64 + lane] = o;
    }
    __syncthreads();
    const float4* Wn4 = (const float4*)Wn;
    f32x4 sum = {0.f, 0.f, 0.f, 0.f};
#pragma unroll 4
    for (int j = 0; j < 64; ++j) {
      float xv = xl[w][j * 16 + (lane >> 2)];
      float4 wv = Wn4[j * 64 + lane];
      sum[0] += xv * wv.x; sum[1] += xv * wv.y; sum[2] += xv * wv.z; sum[3] += xv * wv.w;
    }
#pragma unroll
    for (int m = 4; m < 64; m <<= 1) {
      sum[0] += __shfl_xor(sum[0], m);
      sum[1] += __shfl_xor(sum[1], m);
      sum[2] += __shfl_xor(sum[2], m);
      sum[3] += __shfl_xor(sum[3], m);
    }
    if (lane < 4) {
      int b = row >> 11, s = row & 2047;
#pragma unroll
      for (int e = 0; e < 4; ++e) {
        int h = lane * 4 + e;
        float nv = sum[e] + bn[h];
        invn[((size_t)(b * Hh + h)) * Ss + s] = expf(-nv);
      }
    }
  } else {
    float (*t)[33] = (float(*)[33])smem;
    int ti = bi - 1024;
    const float* W; unsigned short* Wt; int N, n0, k0;
    if (ti < 2048) {
      W = Wqk; Wt = wprojT; N = 2048;
      n0 = (ti & 63) * 32; k0 = (ti >> 6) * 32;
    } else if (ti < 3072) {
      int l = ti - 2048; W = Wv; Wt = wprojT + (size_t)2048 * 1024; N = 1024;
      n0 = (l & 31) * 32; k0 = (l >> 5) * 32;
    } else {
      int l = ti - 3072; W = Wo; Wt = woT; N = 1024;
      n0 = (l & 31) * 32; k0 = (l >> 5) * 32;
    }
    int tx = tid & 31, ty = tid >> 5;
#pragma unroll
    for (int j = 0; j < 32; j += 8)
      t[ty + j][tx] = W[(size_t)(k0 + ty + j) * N + n0 + tx];
    __syncthreads();
#pragma unroll
    for (int j = 0; j < 32; j += 8)
      Wt[(size_t)(n0 + ty + j) * 1024 + k0 + tx] = f2bf(t[tx][ty + j]);
  }
}

// ---------- fused projection GEMM: 128x128, 32x32x16 MFMA (R17 proven) ----------
__global__ __launch_bounds__(256, 4) void k_gemm_proj(
    const unsigned short* __restrict__ A, const unsigned short* __restrict__ BT,
    const float* __restrict__ bias0, const float* __restrict__ bias1,
    void* __restrict__ out0, void* __restrict__ out1, void* __restrict__ out2,
    void* __restrict__ out3, int M, int N, int K) {
  __shared__ __align__(16) unsigned short SMEM[2 * 128 * 64];   // 32 KB, reused by epilogue
  unsigned short* As = SMEM;
  unsigned short* Bs = SMEM + 128 * 64;
  int tid = threadIdx.x, w = tid >> 6, lane = tid & 63;
  int bid = blockIdx.y * gridDim.x + blockIdx.x;   // 0..767
  int xcd = bid & 7, idx = bid >> 3;               // idx 0..95
  int m0 = (xcd * 4 + (idx & 3)) * 128;
  int n0 = (idx >> 2) * 128;
  int wm = w >> 1, wn = w & 1;
  f32x16 acc[2][2] = {};

  int g = lane >> 5;                               // k-half within 16-k granule pair
  int l31 = lane & 31;

  int csrc = 8 * ((lane & 7) ^ (lane >> 3));       // pre-swizzled source column (elements)
  int rst  = w * 8 + (lane >> 3);                  // staging row base (+ i*32)

  for (int kt = 0; kt < (K >> 6); ++kt) {
#pragma unroll
    for (int i = 0; i < 4; ++i) {
      int r = i * 32 + rst;
      gload_lds16(A + (size_t)(m0 + r) * K + kt * 64 + csrc, As + i * 2048 + w * 512);
    }
#pragma unroll
    for (int i = 0; i < 4; ++i) {
      int r = i * 32 + rst;
      gload_lds16(BT + (size_t)(n0 + r) * K + kt * 64 + csrc, Bs + i * 2048 + w * 512);
    }
    __syncthreads();
#pragma unroll
    for (int s = 0; s < 4; ++s) {
      bf16x8 am[2], bn2[2];
#pragma unroll
      for (int mi = 0; mi < 2; ++mi) {
        int R = wm * 64 + mi * 32 + l31;
        am[mi] = *(const bf16x8*)((const char*)As + R * 128 + 16 * (((s * 2 + g) ^ (R & 7))));
      }
#pragma unroll
      for (int ni = 0; ni < 2; ++ni) {
        int R = wn * 64 + ni * 32 + l31;
        bn2[ni] = *(const bf16x8*)((const char*)Bs + R * 128 + 16 * (((s * 2 + g) ^ (R & 7))));
      }
#pragma unroll
      for (int mi = 0; mi < 2; ++mi)
#pragma unroll
        for (int ni = 0; ni < 2; ++ni)
          acc[mi][ni] = __builtin_amdgcn_mfma_f32_32x32x16_bf16(am[mi], bn2[ni], acc[mi][ni], 0, 0, 0);
    }
    __syncthreads();   // WAR seal; after last iter SMEM is dead -> epilogue may reuse
  }

  // ---- epilogue (32x32 C/D mapping, R16/R17-verified) ----
  int nfirst = n0 + wn * 64;                 // multiple of 64, wave-uniform
  int region = nfirst >> 10;
  int bI = m0 >> 11;                         // block-uniform batch
  int tb = (m0 & 2047) + wm * 64;            // wave's t-base within batch
  unsigned short* eplds = SMEM + w * 4096;   // per-wave 64x64 ushort slice (8 KB)

#pragma unroll
  for (int mi = 0; mi < 2; ++mi) {
#pragma unroll
    for (int ni = 0; ni < 2; ++ni) {
      int n = nfirst + ni * 32 + l31;
      float bb = (region < 2) ? bias0[n] : bias1[n - 2048];
      if (region <= 1) {
#pragma unroll
        for (int reg = 0; reg < 16; ++reg) {
          int tl = mi * 32 + (reg & 3) + 8 * (reg >> 2) + 4 * g;   // 0..63
          int col = ni * 32 + l31;                                 // 0..63 (= d)
          eplds[tl * 64 + (col ^ ((tl & 7) << 3))] = f2bf(acc[mi][ni][reg] + bb);
        }
        if (region == 1) {  // kT [bh][d][t] direct (t-contiguous reg-quads)
          int h = (n >> 6) & 15, d = n & 63;
#pragma unroll
          for (int q4 = 0; q4 < 4; ++q4) {
            int t = tb + mi * 32 + 8 * q4 + 4 * g;
            ushort4 o;
            o.x = f2bf(acc[mi][ni][4 * q4 + 0] + bb);
            o.y = f2bf(acc[mi][ni][4 * q4 + 1] + bb);
            o.z = f2bf(acc[mi][ni][4 * q4 + 2] + bb);
            o.w = f2bf(acc[mi][ni][4 * q4 + 3] + bb);
            *(ushort4*)((unsigned short*)out2 + ((size_t)(bI * Hh + h) * Hd + d) * Ss + t) = o;
          }
        }
      } else {            // vT [bh][d][t] direct
        int h = (n >> 6) & 15, d = n & 63;
#pragma unroll
        for (int q4 = 0; q4 < 4; ++q4) {
          int t = tb + mi * 32 + 8 * q4 + 4 * g;
          ushort4 o;
          o.x = f2bf(acc[mi][ni][4 * q4 + 0] + bb);
          o.y = f2bf(acc[mi][ni][4 * q4 + 1] + bb);
          o.z = f2bf(acc[mi][ni][4 * q4 + 2] + bb);
          o.w = f2bf(acc[mi][ni][4 * q4 + 3] + bb);
          *(ushort4*)((unsigned short*)out3 + ((size_t)(bI * Hh + h) * Hd + d) * Ss + t) = o;
        }
      }
    }
  }
  if (region <= 1) {
    asm volatile("" ::: "memory");           // order LDS reads after writes (wave-private slice)
    int tl = lane;                           // one 128B row per lane
    int t = tb + tl;
    int h = (nfirst >> 6) & 15;
    unsigned short* dst = ((region == 0) ? (unsigned short*)out0 : (unsigned short*)out1)
                        + (((size_t)(bI * Hh + h)) * Ss + t) * Hd;
#pragma unroll
    for (int c = 0; c < 8; ++c) {
      int col = (c * 8) ^ ((tl & 7) << 3);
      *(float4*)(dst + c * 8) = *(const float4*)(eplds + tl * 64 + col);
    }
  }
}

// ---------- output GEMM: 64x128 tile, 2-phase dbuf + XCD swizzle + T2 swizzle (R14 proven) ----------
__global__ __launch_bounds__(256, 3) void k_gemm_o(
    const unsigned short* __restrict__ A, const unsigned short* __restrict__ BT,
    const float* __restrict__ bias, float* __restrict__ out) {
  constexpr int K = 1024, N = 1024;
  __shared__ __align__(16) unsigned short As[2][64 * 64];
  __shared__ __align__(16) unsigned short Bs[2][128 * 64];
  int tid = threadIdx.x, w = tid >> 6, lane = tid & 63;
  int bid = blockIdx.y * gridDim.x + blockIdx.x;   // 0..511
  int xcd = bid & 7, idx = bid >> 3;               // 0..63
  int m0 = (xcd * 8 + (idx & 7)) * 64;
  int n0 = (idx >> 3) * 128;
  int wm = w >> 1, wn = w & 1;
  f32x4 acc[2][4] = {};

  int csrc = 8 * ((lane & 7) ^ (lane >> 3));
  int rst  = w * 8 + (lane >> 3);
  int rxor = (lane & 7) << 3;

  auto STAGE = [&](int kt, int cur) {
#pragma unroll
    for (int i = 0; i < 2; ++i) {
      int r = i * 32 + rst;
      gload_lds16(A + (size_t)(m0 + r) * K + kt * 64 + csrc, As[cur] + i * 2048 + w * 512);
    }
#pragma unroll
    for (int i = 0; i < 4; ++i) {
      int r = i * 32 + rst;
      gload_lds16(BT + (size_t)(n0 + r) * K + kt * 64 + csrc, Bs[cur] + i * 2048 + w * 512);
    }
  };

  constexpr int NT = K >> 6;
  STAGE(0, 0);
  __syncthreads();
  for (int kt = 0; kt < NT; ++kt) {
    int cur = kt & 1;
    if (kt + 1 < NT) STAGE(kt + 1, cur ^ 1);
#pragma unroll
    for (int ks = 0; ks < 2; ++ks) {
      int foff = (ks * 32 + (lane >> 4) * 8) ^ rxor;
      bf16x8 af[2], bfr[4];
#pragma unroll
      for (int mt = 0; mt < 2; ++mt)
        af[mt] = *(const bf16x8*)(As[cur] + (wm * 32 + mt * 16 + (lane & 15)) * 64 + foff);
#pragma unroll
      for (int nt = 0; nt < 4; ++nt)
        bfr[nt] = *(const bf16x8*)(Bs[cur] + (wn * 64 + nt * 16 + (lane & 15)) * 64 + foff);
#pragma unroll
      for (int mt = 0; mt < 2; ++mt)
#pragma unroll
        for (int nt = 0; nt < 4; ++nt)
          acc[mt][nt] = __builtin_amdgcn_mfma_f32_16x16x32_bf16(af[mt], bfr[nt], acc[mt][nt], 0, 0, 0);
    }
    __syncthreads();
  }

#pragma unroll
  for (int mt = 0; mt < 2; ++mt) {
#pragma unroll
    for (int nt = 0; nt < 4; ++nt) {
      int n = n0 + wn * 64 + nt * 16 + (lane & 15);
      int m = m0 + wm * 32 + mt * 16 + (lane >> 4) * 4;
      float bb = bias[n];
#pragma unroll
      for (int r = 0; r < 4; ++r)
        out[(size_t)(m + r) * N + n] = acc[mt][nt][r] + bb;
    }
  }
}

// ---------- pass A1: per-chunk gram ----------
__global__ __launch_bounds__(64) void k_gram(
    const unsigned short* __restrict__ vT, const unsigned short* __restrict__ kT,
    unsigned short* __restrict__ G) {
  int lane = threadIdx.x;
  int j = blockIdx.x, bh = blockIdx.y;
  int t0 = j * 64;
  const unsigned short* vb = vT + (size_t)bh * Hd * Ss;
  const unsigned short* kb = kT + (size_t)bh * Hd * Ss;
  unsigned short* g = G + ((size_t)bh * NCH + j) * 4096;

  bf16x8 af[4][2], bfr[4][2];
#pragma unroll
  for (int mt = 0; mt < 4; ++mt)
#pragma unroll
    for (int ks = 0; ks < 2; ++ks) {
      af[mt][ks]  = *(const bf16x8*)(vb + (size_t)(mt * 16 + (lane & 15)) * Ss + t0 + ks * 32 + (lane >> 4) * 8);
      bfr[mt][ks] = *(const bf16x8*)(kb + (size_t)(mt * 16 + (lane & 15)) * Ss + t0 + ks * 32 + (lane >> 4) * 8);
    }
  f32x4 acc[4][4] = {};
#pragma unroll
  for (int mt = 0; mt < 4; ++mt)
#pragma unroll
    for (int nt = 0; nt < 4; ++nt)
#pragma unroll
      for (int ks = 0; ks < 2; ++ks)
        acc[mt][nt] = __builtin_amdgcn_mfma_f32_16x16x32_bf16(af[mt][ks], bfr[nt][ks], acc[mt][nt], 0, 0, 0);
#pragma unroll
  for (int mt = 0; mt < 4; ++mt)
#pragma unroll
    for (int nt = 0; nt < 4; ++nt)
#pragma unroll
      for (int r = 0; r < 4; ++r)
        g[(mt * 16 + (lane >> 4) * 4 + r) * 64 + nt * 16 + (lane & 15)] = f2bf(acc[mt][nt][r]);
}

// ---------- pass A2: exclusive prefix over chunks ----------
__global__ __launch_bounds__(256) void k_prefix(
    const unsigned short* __restrict__ G, unsigned short* __restrict__ Sp) {
  int gidx = blockIdx.x * 256 + threadIdx.x;   // 32 bh * 4096 elems
  int bh = gidx >> 12, e = gidx & 4095;
  const unsigned short* gp = G + (size_t)bh * NCH * 4096 + e;
  unsigned short* sp = Sp + (size_t)bh * NCH * 4096 + e;
  float acc = 0.f;
#pragma unroll
  for (int j = 0; j < NCH; ++j) {
    sp[(size_t)j * 4096] = f2bf(acc);
    acc += bf2f(gp[(size_t)j * 4096]);
  }
}

// ---------- pass B: per-chunk attention (NEW: coalesced ctx stores via P roundtrip) ----------
__global__ __launch_bounds__(256, 6) void k_chunk_attn(
    const unsigned short* __restrict__ q, const unsigned short* __restrict__ k,
    const unsigned short* __restrict__ vT, const unsigned short* __restrict__ Sp,
    const float* __restrict__ invn, unsigned short* __restrict__ ctx) {
  __shared__ __align__(16) unsigned short P[4 * 16 * 64];
  int tid = threadIdx.x, w = tid >> 6, lane = tid & 63;
  int j = blockIdx.x, bh = blockIdx.y;
  int t0 = j * 64;
  const unsigned short* qb = q + (size_t)bh * Ss * Hd;
  const unsigned short* kb = k + (size_t)bh * Ss * Hd;
  const unsigned short* vb = vT + (size_t)bh * Hd * Ss;
  const unsigned short* sp = Sp + ((size_t)bh * NCH + j) * 4096;

  bf16x8 qf[2];
#pragma unroll
  for (int ks = 0; ks < 2; ++ks)
    qf[ks] = *(const bf16x8*)(qb + (size_t)(t0 + w * 16 + (lane & 15)) * Hd + ks * 32 + (lane >> 4) * 8);

  f32x4 acc[4] = {};
#pragma unroll
  for (int nt = 0; nt < 4; ++nt)
#pragma unroll
    for (int ks = 0; ks < 2; ++ks) {
      bf16x8 sf = *(const bf16x8*)(sp + (nt * 16 + (lane & 15)) * 64 + ks * 32 + (lane >> 4) * 8);
      acc[nt] = __builtin_amdgcn_mfma_f32_16x16x32_bf16(qf[ks], sf, acc[nt], 0, 0, 0);
    }

  f32x4 sacc[4] = {};
#pragma unroll
  for (int nt = 0; nt < 4; ++nt)
#pragma unroll
    for (int ks = 0; ks < 2; ++ks) {
      bf16x8 kf = *(const bf16x8*)(kb + (size_t)(t0 + nt * 16 + (lane & 15)) * Hd + ks * 32 + (lane >> 4) * 8);
      sacc[nt] = __builtin_amdgcn_mfma_f32_16x16x32_bf16(qf[ks], kf, sacc[nt], 0, 0, 0);
    }

#pragma unroll
  for (int nt = 0; nt < 4; ++nt)
#pragma unroll
    for (int r = 0; r < 4; ++r) {
      int row = (lane >> 4) * 4 + r;
      int s_local = nt * 16 + (lane & 15);
      float vv = (s_local <= w * 16 + row) ? sacc[nt][r] : 0.f;
      int cb = s_local * 2;
      int byte = w * 2048 + row * 128 + (cb ^ ((row & 7) << 4));
      *(unsigned short*)((char*)P + byte) = f2bf(vv);
    }
  asm volatile("" ::: "memory");

  bf16x8 pf[2];
#pragma unroll
  for (int ks = 0; ks < 2; ++ks) {
    int prow = lane & 15;
    int pcb = (ks * 32 + (lane >> 4) * 8) * 2;
    pf[ks] = *(const bf16x8*)((char*)P + w * 2048 + prow * 128 + (pcb ^ ((prow & 7) << 4)));
  }
#pragma unroll
  for (int dt = 0; dt < 4; ++dt)
#pragma unroll
    for (int ks = 0; ks < 2; ++ks) {
      bf16x8 vf = *(const bf16x8*)(vb + (size_t)(dt * 16 + (lane & 15)) * Ss + t0 + ks * 32 + (lane >> 4) * 8);
      acc[dt] = __builtin_amdgcn_mfma_f32_16x16x32_bf16(pf[ks], vf, acc[dt], 0, 0, 0);
    }

  // epilogue: scale by invn, stage per-wave 16x64 patch in P (dead after pf loads;
  // same-wave DS ordering makes reuse safe), then coalesced 128B-row ctx writes.
  int b = bh >> 4, h = bh & 15;
  float sc[4];
#pragma unroll
  for (int r = 0; r < 4; ++r)
    sc[r] = invn[(size_t)bh * Ss + t0 + w * 16 + (lane >> 4) * 4 + r];
  unsigned short* ep = P + w * 1024;           // per-wave 16x64 ushort slice
  asm volatile("" ::: "memory");
#pragma unroll
  for (int dt = 0; dt < 4; ++dt)
#pragma unroll
    for (int r = 0; r < 4; ++r) {
      int rr = (lane >> 4) * 4 + r;            // 0..15 (t-row within wave)
      int col = dt * 16 + (lane & 15);         // 0..63 (= d)
      ep[rr * 64 + (col ^ ((rr & 7) << 3))] = f2bf(acc[dt][r] * sc[r]);
    }
  asm volatile("" ::: "memory");
  {
    int rr = lane & 15, qd = lane >> 4;        // 4 lanes per row, 32B each
    int t = t0 + w * 16 + rr;
    unsigned short* dst = ctx + ((size_t)b * Ss + t) * Dm + h * Hd + qd * 16;
#pragma unroll
    for (int jj = 0; jj < 2; ++jj) {
      int c0 = qd * 16 + jj * 8;
      *(float4*)(dst + jj * 8) = *(const float4*)(ep + rr * 64 + (c0 ^ ((rr & 7) << 3)));
    }
  }
}

// ---------- launch ----------
extern "C" void kernel_launch(void* const* d_in, const int* in_sizes, int n_in,
                              void* d_out, int out_size, void* d_ws, size_t ws_size,
                              hipStream_t stream) {
  const float* x   = (const float*)d_in[0];
  const float* Wqk = (const float*)d_in[1];
  const float* bqk = (const float*)d_in[2];
  const float* Wv  = (const float*)d_in[3];
  const float* bv  = (const float*)d_in[4];
  const float* Wn  = (const float*)d_in[5];
  const float* bn  = (const float*)d_in[6];
  const float* Wo  = (const float*)d_in[7];
  const float* bo  = (const float*)d_in[8];

  char* ws = (char*)d_ws;
  size_t off = 0;
  unsigned short* xb    = (unsigned short*)(ws + off); off += (size_t)Mtot * Dm * 2;          // 8 MB
  unsigned short* wprojT= (unsigned short*)(ws + off); off += (size_t)3072 * 1024 * 2;        // 6 MB
  unsigned short* woT   = (unsigned short*)(ws + off); off += (size_t)1024 * 1024 * 2;        // 2 MB
  unsigned short* qbuf  = (unsigned short*)(ws + off); off += (size_t)Bb * Hh * Ss * Hd * 2;  // 8 MB
  unsigned short* kbuf  = (unsigned short*)(ws + off); off += (size_t)Bb * Hh * Ss * Hd * 2;  // 8 MB
  unsigned short* ktbuf = (unsigned short*)(ws + off); off += (size_t)Bb * Hh * Ss * Hd * 2;  // 8 MB
  unsigned short* vbuf  = (unsigned short*)(ws + off); off += (size_t)Bb * Hh * Ss * Hd * 2;  // 8 MB
  float* invn           = (float*)(ws + off);          off += (size_t)Bb * Hh * Ss * 4;       // 256 KB
  unsigned short* G     = (unsigned short*)(ws + off); off += (size_t)Bb * Hh * NCH * 4096 * 2; // 8 MB
  unsigned short* Sp    = (unsigned short*)(ws + off); off += (size_t)Bb * Hh * NCH * 4096 * 2; // 8 MB
  unsigned short* ctx   = xb;  // alias: xb dead after fused projection GEMM

  // 1) fused prep (one launch)
  k_prep<<<5120, 256, 0, stream>>>(x, Wn, bn, invn, xb, Wqk, Wv, Wo, wprojT, woT);

  // 2) fused q/k/v projections (N = 3072), 32x32x16 MFMA + R14 staging (768 blocks)
  k_gemm_proj<<<dim3(3072 / 128, Mtot / 128), 256, 0, stream>>>(
      xb, wprojT, bqk, bv, qbuf, kbuf, ktbuf, vbuf, Mtot, 3072, 1024);

  // 3) attention = parallel gram + parallel prefix + per-chunk
  k_gram<<<dim3(NCH, Bb * Hh), 64, 0, stream>>>(vbuf, ktbuf, G);
  k_prefix<<<(Bb * Hh * 4096) / 256, 256, 0, stream>>>(G, Sp);
  k_chunk_attn<<<dim3(NCH, Bb * Hh), 256, 0, stream>>>(qbuf, kbuf, vbuf, Sp, invn, ctx);

  // 4) output projection -> f32 d_out, 64x128 2-phase dbuf + XCD + T2 swizzle (512 blocks)
  k_gemm_o<<<dim3(1024 / 128, Mtot / 64), 256, 0, stream>>>(ctx, woT, bo, (float*)d_out);
}